// Round 14
// baseline (282.608 us; speedup 1.0000x reference)
//
#include <hip/hip_runtime.h>
#include <hip/hip_bf16.h>
#include <cstdint>
#include <cstddef>

// Problem constants
#define BMC 32    // B*M
#define NNODE 1024
#define DIN 128
#define PPROJ 64
#define NCLUS 10
#define FOUT 128
#define KNB 10

typedef _Float16 half8 __attribute__((ext_vector_type(8)));
typedef float f32x4 __attribute__((ext_vector_type(4)));

// Inputs: fp32 (probe-confirmed). Output: fp32. Internals fp32 except:
//  - Z stored as fp16 split pair Zh/Zl (lo scaled x2048) for MFMA Gram
//  - Ek bf16 (overlays dead Zh/Zl region after k_topk)
// X_trans fp32 (16 MB) lives in d_out; k_final overwrites d_out with output.
static const size_t OFF_Z    = 0;          // words [0,1048576): Zh fp16; [1048576,2097152): Zl fp16
static const size_t OFF_SQ   = 2097152;    // 32,768     ||Z||^2 fp32
static const size_t OFF_HC   = 2129920;    // 327,680    softmax cluster H fp32
static const size_t OFF_IDX  = 2457600;    // 327,680    (int) knn indices
static const size_t OFF_CNT  = 2785280;    // 32,768     (int) edge in-degree  [zeroed in k_split]
static const size_t OFF_FILL = 2818048;    // 32,768     hosts pre-split weights
static const size_t OFF_EC   = 2850816;    // 40,960     cluster edge feats    [zeroed in k_split]
static const size_t OFF_DCV  = 2891776;    // 320        cluster edge degrees  [zeroed in k_split]
static const size_t OFF_OFFS = 2892096;    // 32,768     (int) CSR offsets
static const size_t OFF_ADJ  = 2924864;    // 327,680    (int) CSR adjacency
static const size_t OFF_FLAG = 3252544;    // 1          (int) input-dtype flag
static const size_t OFF_END  = 3252608;
static const size_t OFF_WPH  = OFF_FILL;          // 4096 words  (8192 fp16)
static const size_t OFF_WPL  = OFF_FILL +  4096;  // 4096 words
static const size_t OFF_THH  = OFF_FILL +  8192;  // 8192 words  (16384 fp16)
static const size_t OFF_THL  = OFF_FILL + 16384;  // ends at +24576 < 32768

__device__ __forceinline__ float bfu(unsigned int lo16) {
    return __uint_as_float(lo16 << 16);
}
__device__ __forceinline__ float ldf(const void* p, size_t i, bool isbf) {
    return isbf ? bfu((unsigned int)((const unsigned short*)p)[i])
                : ((const float*)p)[i];
}
__device__ __forceinline__ unsigned short f2bf(float v) {
    __hip_bfloat16 h = __float2bfloat16(v);
    return *(unsigned short*)&h;
}

// --- top-k helpers: u64 sortable keys (R5-measured-best transform) --------
__device__ __forceinline__ unsigned long long mkkey(float v, int col) {
    unsigned int bits = __float_as_uint(v);
    unsigned int s = bits ^ (0x80000000u | (unsigned int)((int)bits >> 31));
    return ((unsigned long long)s << 32) | (unsigned int)col;
}
__device__ __forceinline__ void kcas(unsigned long long &a, unsigned long long &b) {
    bool c = b < a;
    unsigned long long t = c ? b : a;
    b = c ? a : b;
    a = t;
}
__device__ __forceinline__ void kmin(unsigned long long &a, unsigned long long b) {
    a = (b < a) ? b : a;
}

// ---------------------------------------------------------------------------
// R19: weight split + per-block probe + cnt/Ec/Dcv zeroing (unchanged).
// ---------------------------------------------------------------------------
__global__ __launch_bounds__(256) void k_split(const unsigned int* __restrict__ xw,
                                               const void* __restrict__ Wp,
                                               const void* __restrict__ Th,
                                               int* __restrict__ flag,
                                               _Float16* __restrict__ WpH,
                                               _Float16* __restrict__ WpL,
                                               _Float16* __restrict__ ThH,
                                               _Float16* __restrict__ ThL,
                                               int* __restrict__ cntz,
                                               float* __restrict__ EcZ) {
    __shared__ int red[256];
    int t = threadIdx.x;
    int c = 0;
    for (int i = t; i < 1024; i += 256) {
        float b = bfu(xw[i] & 0xffffu);
        float ab = fabsf(b);
        if (ab > 9.5e-7f && ab < 1.0e6f) c++;
    }
    red[t] = c;
    __syncthreads();
    for (int off = 128; off > 0; off >>= 1) {
        if (t < off) red[t] += red[t + off];
        __syncthreads();
    }
    const bool isbf = (red[0] >= 700);
    if (blockIdx.x == 0 && t == 0) flag[0] = isbf ? 1 : 0;

    int i = blockIdx.x * 256 + t;   // 0..24575
    cntz[i] = 0;
    if (i < 8192) cntz[i + 24576] = 0;        // cnt: 32768 words
    EcZ[i] = 0.0f;
    if (i < 16704) EcZ[i + 24576] = 0.0f;     // Ec+Dcv: 41280 words

    if (i < 8192) {
        float v = ldf(Wp, i, isbf);
        _Float16 h = (_Float16)v;
        WpH[i] = h;
        WpL[i] = (_Float16)((v - (float)h) * 2048.0f);
    } else {
        int j = i - 8192;
        float v = ldf(Th, j, isbf);
        _Float16 h = (_Float16)v;
        ThH[j] = h;
        ThL[j] = (_Float16)((v - (float)h) * 2048.0f);
    }
}

// ---------------------------------------------------------------------------
// Kernel 1 (R13, unchanged): Z = x_flat @ Wp^T + b via fp16-split MFMA.
// ---------------------------------------------------------------------------
__global__ __launch_bounds__(256) void k_proj(const void* __restrict__ x,
                                              const _Float16* __restrict__ WpH,
                                              const _Float16* __restrict__ WpL,
                                              const void* __restrict__ Wpb,
                                              const void* __restrict__ Cm,
                                              const int* __restrict__ flag,
                                              _Float16* __restrict__ Zh,
                                              _Float16* __restrict__ Zl,
                                              float* __restrict__ sqv,
                                              float* __restrict__ Hc) {
    __shared__ __align__(16) _Float16 wps[2][64][72];
    __shared__ __align__(16) _Float16 xsh[2][32][72];
    __shared__ float zs[32][68];
    __shared__ float cs[10][64];

    const bool isbf = (flag[0] != 0);
    int tid = threadIdx.x;
    int bi  = blockIdx.x;
    int bm  = bi >> 5;
    int n0  = (bi & 31) << 5;
    int b   = bm >> 3, m = bm & 7;

    int lane = tid & 63, wave = tid >> 6;
    int m16 = lane & 15, quad = lane >> 4;
    int rh = wave >> 1, ch = wave & 1;

    for (int e = tid; e < 640; e += 256) cs[e >> 6][e & 63] = ldf(Cm, e, isbf);

    f32x4 aH[2], aX[2];
#pragma unroll
    for (int t = 0; t < 2; ++t) {
        aH[t] = (f32x4){0.f, 0.f, 0.f, 0.f};
        aX[t] = (f32x4){0.f, 0.f, 0.f, 0.f};
    }

    for (int kc = 0; kc < 2; ++kc) {
        __syncthreads();
        for (int e = tid; e < 512; e += 256) {
            int p = e >> 3, c = e & 7;
            *(uint4*)&wps[0][p][c * 8] =
                *(const uint4*)(WpH + (size_t)p * 128 + kc * 64 + c * 8);
            *(uint4*)&wps[1][p][c * 8] =
                *(const uint4*)(WpL + (size_t)p * 128 + kc * 64 + c * 8);
        }
        for (int e = tid; e < 2048; e += 256) {
            int r = e >> 6, dk = e & 63;
            float v = ldf(x, (((size_t)b * NNODE + n0 + r) * 8 + m) * DIN + kc * 64 + dk, isbf);
            _Float16 h = (_Float16)v;
            xsh[0][r][dk] = h;
            xsh[1][r][dk] = (_Float16)((v - (float)h) * 2048.0f);
        }
        __syncthreads();
#pragma unroll
        for (int c32 = 0; c32 < 2; ++c32) {
            half8 Ah = *(const half8*)&xsh[0][rh * 16 + m16][c32 * 32 + quad * 8];
            half8 Al = *(const half8*)&xsh[1][rh * 16 + m16][c32 * 32 + quad * 8];
#pragma unroll
            for (int t = 0; t < 2; ++t) {
                int p = ch * 32 + t * 16 + m16;
                half8 Bh = *(const half8*)&wps[0][p][c32 * 32 + quad * 8];
                half8 Bl = *(const half8*)&wps[1][p][c32 * 32 + quad * 8];
                aH[t] = __builtin_amdgcn_mfma_f32_16x16x32_f16(Ah, Bh, aH[t], 0, 0, 0);
                aX[t] = __builtin_amdgcn_mfma_f32_16x16x32_f16(Al, Bh, aX[t], 0, 0, 0);
                aX[t] = __builtin_amdgcn_mfma_f32_16x16x32_f16(Ah, Bl, aX[t], 0, 0, 0);
            }
        }
    }

#pragma unroll
    for (int t = 0; t < 2; ++t) {
        int p = ch * 32 + t * 16 + m16;
        float bias = ldf(Wpb, p, isbf);
#pragma unroll
        for (int r = 0; r < 4; ++r) {
            int row = rh * 16 + quad * 4 + r;
            float v = aH[t][r] + aX[t][r] * (1.0f / 2048.0f) + bias;
            zs[row][p] = v;
            size_t off = ((size_t)bm * NNODE + n0 + row) * 64 + p;
            _Float16 h = (_Float16)v;
            Zh[off] = h;
            Zl[off] = (_Float16)((v - (float)h) * 2048.0f);
        }
    }
    __syncthreads();

    int row = tid >> 3, slot = tid & 7;
    int d0 = slot * 8;
    float sp = 0.f;
#pragma unroll
    for (int dd = 0; dd < 8; ++dd) { float z = zs[row][d0+dd]; sp += z * z; }
#pragma unroll
    for (int mm = 1; mm < 8; mm <<= 1) sp += __shfl_xor(sp, mm, 8);
    size_t g = (size_t)bm * NNODE + n0 + row;
    if (slot == 0) sqv[g] = sp;

    float sc[10];
#pragma unroll
    for (int c = 0; c < 10; ++c) {
        float pa = 0.f;
#pragma unroll
        for (int dd = 0; dd < 8; ++dd) pa += zs[row][d0+dd] * cs[c][d0+dd];
#pragma unroll
        for (int mm = 1; mm < 8; mm <<= 1) pa += __shfl_xor(pa, mm, 8);
        sc[c] = pa;
    }
    float mx = sc[0];
#pragma unroll
    for (int c = 1; c < 10; ++c) mx = fmaxf(mx, sc[c]);
    float ssum = 0.f;
#pragma unroll
    for (int c = 0; c < 10; ++c) { sc[c] = expf(sc[c] - mx); ssum += sc[c]; }
    float inv = 1.0f / ssum;
#pragma unroll
    for (int c = 0; c < 10; ++c)
        if ((c & 7) == slot) Hc[g * 10 + c] = sc[c] * inv;
}

// ---------------------------------------------------------------------------
// R22: MERGED top-K + Theta GEMM dispatch. Even blocks run the R13-best
// top-K (VALU/L2-latency-bound, 24% occupancy standalone); odd blocks run
// the Theta MFMA GEMM (MFMA/LDS-bound, independent of top-K). Interleaved
// mapping mixes both profiles on each CU — theta work issues in the cycles
// topk spends stalled (m114 co-scheduling: time ~ max, not sum).
// LDS is a union (41.5KB = theta's need; topk uses 9KB of it).
// ---------------------------------------------------------------------------
#define TOPK_SELECT(J0)                                                        \
  {                                                                            \
    unsigned long long b0 = mkkey(ST[(sslot     ) * 36 + srow], (J0) + sslot);        \
    unsigned long long b1 = mkkey(ST[(sslot +  8) * 36 + srow], (J0) + sslot + 8);    \
    unsigned long long b2 = mkkey(ST[(sslot + 16) * 36 + srow], (J0) + sslot + 16);   \
    unsigned long long b3 = mkkey(ST[(sslot + 24) * 36 + srow], (J0) + sslot + 24);   \
    unsigned long long b4 = mkkey(ST[(sslot + 32) * 36 + srow], (J0) + sslot + 32);   \
    unsigned long long b5 = mkkey(ST[(sslot + 40) * 36 + srow], (J0) + sslot + 40);   \
    unsigned long long b6 = mkkey(ST[(sslot + 48) * 36 + srow], (J0) + sslot + 48);   \
    unsigned long long b7 = mkkey(ST[(sslot + 56) * 36 + srow], (J0) + sslot + 56);   \
    kcas(b0, b1); kcas(b2, b3); kcas(b4, b5); kcas(b6, b7);                    \
    kcas(b0, b2); kcas(b1, b3); kcas(b4, b6); kcas(b5, b7);                    \
    kcas(b1, b2); kcas(b5, b6);                                                \
    kcas(b0, b4); kcas(b1, b5); kcas(b2, b6); kcas(b3, b7);                    \
    kcas(b2, b4); kcas(b3, b5);                                                \
    kcas(b1, b2); kcas(b3, b4); kcas(b5, b6);                                  \
    kmin(keys[2], b7); kmin(keys[3], b6); kmin(keys[4], b5); kmin(keys[5], b4);\
    kmin(keys[6], b3); kmin(keys[7], b2); kmin(keys[8], b1); kmin(keys[9], b0);\
    kcas(keys[0], keys[8]); kcas(keys[1], keys[9]);                            \
    kcas(keys[2], keys[6]); kcas(keys[3], keys[7]);                            \
    kcas(keys[4], keys[8]); kcas(keys[5], keys[9]);                            \
    kcas(keys[2], keys[4]); kcas(keys[3], keys[5]);                            \
    kcas(keys[6], keys[8]); kcas(keys[7], keys[9]);                            \
    kcas(keys[0], keys[1]); kcas(keys[2], keys[3]);                            \
    kcas(keys[4], keys[5]); kcas(keys[6], keys[7]); kcas(keys[8], keys[9]);    \
  }

#define TOPK_TILE(J0, CH0,CH1,CL0,CL1,CSQ, NH0,NH1,NL0,NL1,NSQ)                \
  {                                                                            \
    f32x4 acc  = {0.f, 0.f, 0.f, 0.f};                                         \
    f32x4 accx = {0.f, 0.f, 0.f, 0.f};                                         \
    acc  = __builtin_amdgcn_mfma_f32_16x16x32_f16(ah0, CH0, acc, 0, 0, 0);     \
    acc  = __builtin_amdgcn_mfma_f32_16x16x32_f16(ah1, CH1, acc, 0, 0, 0);     \
    accx = __builtin_amdgcn_mfma_f32_16x16x32_f16(al0, CH0, accx, 0, 0, 0);    \
    accx = __builtin_amdgcn_mfma_f32_16x16x32_f16(ah0, CL0, accx, 0, 0, 0);    \
    accx = __builtin_amdgcn_mfma_f32_16x16x32_f16(al1, CH1, accx, 0, 0, 0);    \
    accx = __builtin_amdgcn_mfma_f32_16x16x32_f16(ah1, CL1, accx, 0, 0, 0);    \
    f32x4 sc;                                                                  \
    _Pragma("unroll")                                                          \
    for (int r = 0; r < 4; ++r) {                                              \
      float g = acc[r] + accx[r] * (1.0f / 2048.0f);                           \
      sc[r] = fmaf(-2.0f, g, CSQ);                                             \
    }                                                                          \
    *(f32x4*)&ST[cl * 36 + quad * 4] = sc;                                     \
    f32x4 accB  = {0.f, 0.f, 0.f, 0.f};                                        \
    f32x4 accxB = {0.f, 0.f, 0.f, 0.f};                                        \
    accB  = __builtin_amdgcn_mfma_f32_16x16x32_f16(ah0b, CH0, accB, 0, 0, 0);  \
    accB  = __builtin_amdgcn_mfma_f32_16x16x32_f16(ah1b, CH1, accB, 0, 0, 0);  \
    accxB = __builtin_amdgcn_mfma_f32_16x16x32_f16(al0b, CH0, accxB, 0, 0, 0); \
    accxB = __builtin_amdgcn_mfma_f32_16x16x32_f16(ah0b, CL0, accxB, 0, 0, 0); \
    accxB = __builtin_amdgcn_mfma_f32_16x16x32_f16(al1b, CH1, accxB, 0, 0, 0); \
    accxB = __builtin_amdgcn_mfma_f32_16x16x32_f16(ah1b, CL1, accxB, 0, 0, 0); \
    _Pragma("unroll")                                                          \
    for (int r = 0; r < 4; ++r) {                                              \
      float g = accB[r] + accxB[r] * (1.0f / 2048.0f);                         \
      sc[r] = fmaf(-2.0f, g, CSQ);                                             \
    }                                                                          \
    *(f32x4*)&ST[cl * 36 + 16 + quad * 4] = sc;                                \
    {                                                                          \
      const _Float16* pnb = Zhb + (size_t)((J0) + 64 + cl) * 64 + quad * 8;    \
      const _Float16* pnl = Zlb + (size_t)((J0) + 64 + cl) * 64 + quad * 8;    \
      NH0 = *(const half8*)pnb;                                                \
      NH1 = *(const half8*)(pnb + 32);                                         \
      NL0 = *(const half8*)pnl;                                                \
      NL1 = *(const half8*)(pnl + 32);                                         \
      NSQ = sqb[(J0) + 64 + cl];                                               \
    }                                                                          \
    asm volatile("s_waitcnt lgkmcnt(0)" ::: "memory");                         \
    __builtin_amdgcn_s_barrier();                                              \
    asm volatile("" ::: "memory");                                             \
    TOPK_SELECT(J0);                                                           \
    asm volatile("" ::: "memory");                                             \
    __builtin_amdgcn_s_barrier();                                              \
    asm volatile("" ::: "memory");                                             \
  }

__global__ __launch_bounds__(256) void k_topktheta(const _Float16* __restrict__ Zh,
                                                   const _Float16* __restrict__ Zl,
                                                   const float* __restrict__ sqv,
                                                   int* __restrict__ idxo,
                                                   int* __restrict__ cnt,
                                                   const void* __restrict__ x,
                                                   const _Float16* __restrict__ ThH,
                                                   const _Float16* __restrict__ ThL,
                                                   const void* __restrict__ Thb,
                                                   const int* __restrict__ flag,
                                                   float* __restrict__ Xt) {
    __shared__ __align__(16) char smem[41472];
    int tid = threadIdx.x;
    int gbi = blockIdx.x;

    if ((gbi & 1) == 0) {
        // ================= top-K path (R13-measured-best) =================
        float* ST = (float*)smem;    // 64*36 floats = 9216B
        int bi  = gbi >> 1;
        int bm  = bi >> 5;
        int n0  = (bi & 31) << 5;
        const _Float16* Zhb = Zh + (size_t)bm * NNODE * 64;
        const _Float16* Zlb = Zl + (size_t)bm * NNODE * 64;
        const float*    sqb = sqv + (size_t)bm * NNODE;

        int lane = tid & 63, wave = tid >> 6;
        int m16 = lane & 15, quad = lane >> 4;
        int cl = wave * 16 + m16;

        half8 ah0, ah1, al0, al1, ah0b, ah1b, al0b, al1b;
        {
            size_t ab = (size_t)(n0 + m16) * 64 + quad * 8;
            ah0 = *(const half8*)(Zhb + ab);
            ah1 = *(const half8*)(Zhb + ab + 32);
            al0 = *(const half8*)(Zlb + ab);
            al1 = *(const half8*)(Zlb + ab + 32);
            size_t ab2 = ab + 16 * 64;
            ah0b = *(const half8*)(Zhb + ab2);
            ah1b = *(const half8*)(Zhb + ab2 + 32);
            al0b = *(const half8*)(Zlb + ab2);
            al1b = *(const half8*)(Zlb + ab2 + 32);
        }

        unsigned long long keys[10];
#pragma unroll
        for (int j = 0; j < 10; ++j) keys[j] = ~0ULL;

        int srow  = tid >> 3;    // 0..31: this thread's row
        int sslot = tid & 7;     // 8 threads per row

        half8 cbh0, cbh1, cbl0, cbl1, nbh0, nbh1, nbl0, nbl1;
        float csq, nsq;
        {
            const _Float16* pb = Zhb + (size_t)cl * 64 + quad * 8;
            const _Float16* pl = Zlb + (size_t)cl * 64 + quad * 8;
            cbh0 = *(const half8*)pb;
            cbh1 = *(const half8*)(pb + 32);
            cbl0 = *(const half8*)pl;
            cbl1 = *(const half8*)(pl + 32);
            csq  = sqb[cl];
        }

        for (int tp = 0; tp < 8; ++tp) {
            int j0a = tp << 7;
            TOPK_TILE(j0a,      cbh0, cbh1, cbl0, cbl1, csq, nbh0, nbh1, nbl0, nbl1, nsq)
            TOPK_TILE(j0a + 64, nbh0, nbh1, nbl0, nbl1, nsq, cbh0, cbh1, cbl0, cbl1, csq)
        }

        size_t gr = (size_t)bm * NNODE + n0 + srow;
        for (int it = 0; it < 10; ++it) {
            unsigned long long mine = keys[0];
            unsigned long long best = mine;
#pragma unroll
            for (int mm = 1; mm < 8; mm <<= 1) {
                unsigned long long o = __shfl_xor(best, mm, 8);
                if (o < best) best = o;
            }
            if (best == mine) {
#pragma unroll
                for (int j = 0; j < 9; ++j) keys[j] = keys[j+1];
                keys[9] = ~0ULL;
                int col = (int)(best & 0xFFFFFFFFu);
                idxo[gr * KNB + it] = col;
                atomicAdd(&cnt[bm * NNODE + col], 1);
            }
        }
        return;
    }

    // ================= Theta GEMM path (R14 math, aliased LDS) ============
    _Float16* ths0 = (_Float16*)smem;          // [128][72] = 18432B
    _Float16* ths1 = ths0 + 128 * 72;          // [128][72] = 18432B
    _Float16* xsh  = ths1 + 128 * 72;          // [32][72]  =  4608B (41472 total)

    const bool isbf = (flag[0] != 0);
    int bi  = gbi >> 1;
    int bm  = bi >> 5;
    int n0  = (bi & 31) << 5;
    int b   = bm >> 3, m = bm & 7;

    int lane = tid & 63, wave = tid >> 6;
    int m16 = lane & 15, quad = lane >> 4;
    int rh = wave >> 1, ch = wave & 1;

    f32x4 aH[4], aX[4];
#pragma unroll
    for (int t = 0; t < 4; ++t) {
        aH[t] = (f32x4){0.f, 0.f, 0.f, 0.f};
        aX[t] = (f32x4){0.f, 0.f, 0.f, 0.f};
    }

    for (int kc = 0; kc < 2; ++kc) {
        __syncthreads();
        for (int e = tid; e < 1024; e += 256) {
            int f = e >> 3, c = e & 7;
            *(uint4*)&ths0[f * 72 + c * 8] =
                *(const uint4*)(ThH + (size_t)f * 128 + kc * 64 + c * 8);
            *(uint4*)&ths1[f * 72 + c * 8] =
                *(const uint4*)(ThL + (size_t)f * 128 + kc * 64 + c * 8);
        }
        for (int e = tid; e < 2048; e += 256) {
            int r = e >> 6, dk = e & 63;
            float v = ldf(x, (((size_t)b * NNODE + n0 + r) * 8 + m) * DIN + kc * 64 + dk, isbf);
            xsh[r * 72 + dk] = (_Float16)v;
        }
        __syncthreads();
#pragma unroll
        for (int c32 = 0; c32 < 2; ++c32) {
            half8 Ah = *(const half8*)&xsh[(rh * 16 + m16) * 72 + c32 * 32 + quad * 8];
#pragma unroll
            for (int t = 0; t < 4; ++t) {
                int f = ch * 64 + t * 16 + m16;
                half8 Bh = *(const half8*)&ths0[f * 72 + c32 * 32 + quad * 8];
                half8 Bl = *(const half8*)&ths1[f * 72 + c32 * 32 + quad * 8];
                aH[t] = __builtin_amdgcn_mfma_f32_16x16x32_f16(Ah, Bh, aH[t], 0, 0, 0);
                aX[t] = __builtin_amdgcn_mfma_f32_16x16x32_f16(Ah, Bl, aX[t], 0, 0, 0);
            }
        }
    }
#pragma unroll
    for (int t = 0; t < 4; ++t) {
        int f = ch * 64 + t * 16 + m16;
        float bias = ldf(Thb, f, isbf);
        size_t rb = (size_t)bm * NNODE + n0 + rh * 16 + quad * 4;
#pragma unroll
        for (int r = 0; r < 4; ++r) {
            Xt[(rb + r) * 128 + f] = aH[t][r] + aX[t][r] * (1.0f / 2048.0f) + bias;
        }
    }
}
#undef TOPK_TILE
#undef TOPK_SELECT

// ---------------------------------------------------------------------------
// R15: fused CSR build (standalone again — the theta it hid under now runs
// concurrently with top-K).
// ---------------------------------------------------------------------------
__global__ __launch_bounds__(256) void k_csr(const int* __restrict__ cnt,
                                             const int* __restrict__ idxb,
                                             int* __restrict__ offs,
                                             int* __restrict__ adj) {
    __shared__ int part[256];
    __shared__ int fillL[1024];
    int bm = blockIdx.x, t = threadIdx.x;
    int base = bm * 1024 + t * 4;
    int c0 = cnt[base], c1 = cnt[base+1], c2 = cnt[base+2], c3 = cnt[base+3];
    int ps = c0 + c1 + c2 + c3;
    part[t] = ps;
    __syncthreads();
    for (int off = 1; off < 256; off <<= 1) {
        int add = (t >= off) ? part[t - off] : 0;
        __syncthreads();
        part[t] += add;
        __syncthreads();
    }
    int e0 = part[t] - ps;
    int gb = bm * (NNODE * KNB);
    int o0 = gb + e0, o1 = o0 + c0, o2 = o1 + c1, o3 = o2 + c2;
    offs[base]   = o0;
    offs[base+1] = o1;
    offs[base+2] = o2;
    offs[base+3] = o3;
    fillL[t*4]   = o0;
    fillL[t*4+1] = o1;
    fillL[t*4+2] = o2;
    fillL[t*4+3] = o3;
    __syncthreads();
    int ibase = bm * (NNODE * KNB);
    for (int e = t; e < NNODE * KNB; e += 256) {
        int eidx = idxb[ibase + e];                 // edge column in [0,1024)
        int pos = atomicAdd(&fillL[eidx], 1);       // LDS atomic
        adj[pos] = (bm << 10) + (e / 10);           // member node g
    }
}

// ---------------------------------------------------------------------------
// R19: MERGED edge-gather + cluster-edge kernel (unchanged).
// ---------------------------------------------------------------------------
__global__ __launch_bounds__(256) void k_edgeclus(const float* __restrict__ Xt,
                                                  const int* __restrict__ offs,
                                                  const int* __restrict__ cnt,
                                                  const int* __restrict__ adj,
                                                  unsigned short* __restrict__ Ek,
                                                  const float* __restrict__ Hc,
                                                  float* __restrict__ Ec,
                                                  float* __restrict__ Dcv) {
    __shared__ float hcs[128][12];
    int tid = threadIdx.x;
    int bi  = blockIdx.x;

    if (bi < 256) {
        int bm = bi >> 3;
        int ch = bi & 7;
        int n0 = ch * 128;

        for (int e = tid; e < 1280; e += 256) {
            int r = e / 10, c = e - r * 10;
            hcs[r][c] = Hc[((size_t)bm * NNODE + n0 + r) * 10 + c];
        }
        __syncthreads();

        int f = tid & 127;
        int h = tid >> 7;
        int c0 = h * 5;
        float acc[5]  = {0.f,0.f,0.f,0.f,0.f};
        float dacc[5] = {0.f,0.f,0.f,0.f,0.f};
#pragma unroll 2
        for (int n = 0; n < 128; ++n) {
            float xv = Xt[((size_t)bm * NNODE + n0 + n) * 128 + f];
#pragma unroll
            for (int j = 0; j < 5; ++j) {
                float hv = hcs[n][c0 + j];
                acc[j]  = fmaf(hv, xv, acc[j]);
                dacc[j] += hv;
            }
        }
#pragma unroll
        for (int j = 0; j < 5; ++j)
            atomicAdd(&Ec[((size_t)bm * 10 + c0 + j) * 128 + f], acc[j]);
        if (f == 0) {
#pragma unroll
            for (int j = 0; j < 5; ++j) atomicAdd(&Dcv[bm * 10 + c0 + j], dacc[j]);
        }
        return;
    }

    int ebi = bi - 256;
    int swz = (ebi & 7) * 512 + (ebi >> 3);
    int e = swz * 8 + (tid >> 5);
    int l = tid & 31;
    int start = offs[e];
    int num = cnt[e];
    float4 acc = {0.f, 0.f, 0.f, 0.f};
    if (num > 0) {
        int nm1 = num - 1;
        int gidx[16];
#pragma unroll
        for (int j = 0; j < 16; ++j) {
            int jj = (j < nm1) ? j : nm1;
            gidx[j] = adj[start + jj];
        }
#pragma unroll
        for (int j = 0; j < 16; ++j) {
            float4 a = *(const float4*)(Xt + (size_t)gidx[j] * 128 + l * 4);
            float w = (j < num) ? 1.0f : 0.0f;
            acc.x = fmaf(w, a.x, acc.x);
            acc.y = fmaf(w, a.y, acc.y);
            acc.z = fmaf(w, a.z, acc.z);
            acc.w = fmaf(w, a.w, acc.w);
        }
        int i = 16;
        for (; i + 1 < num; i += 2) {
            int g0 = adj[start + i];
            int g1 = adj[start + i + 1];
            float4 a = *(const float4*)(Xt + (size_t)g0 * 128 + l * 4);
            float4 b = *(const float4*)(Xt + (size_t)g1 * 128 + l * 4);
            acc.x += a.x + b.x; acc.y += a.y + b.y;
            acc.z += a.z + b.z; acc.w += a.w + b.w;
        }
        if (i < num) {
            int g0 = adj[start + i];
            float4 a = *(const float4*)(Xt + (size_t)g0 * 128 + l * 4);
            acc.x += a.x; acc.y += a.y; acc.z += a.z; acc.w += a.w;
        }
    }
    float scale = (num > 0) ? 1.0f / (float)num : 0.0f;
    ushort4 o;
    o.x = f2bf(acc.x * scale);
    o.y = f2bf(acc.y * scale);
    o.z = f2bf(acc.z * scale);
    o.w = f2bf(acc.w * scale);
    *(ushort4*)(Ek + (size_t)e * 128 + l * 4) = o;
}

// ---------------------------------------------------------------------------
// Final (R16, unchanged): 32 threads/node, XCD swizzle, folded 1/Dcv,
// batched 10-wide kNN gather.
// ---------------------------------------------------------------------------
__global__ __launch_bounds__(256) void k_final(const unsigned short* __restrict__ Ek,
                                               const float* __restrict__ Ec,
                                               const float* __restrict__ Hc,
                                               const float* __restrict__ Dcv,
                                               const int* __restrict__ idxb,
                                               float* __restrict__ out) {
    int tid = threadIdx.x;
    int bi  = blockIdx.x;
    int swz = (bi & 7) * 512 + (bi >> 3);
    int g = swz * 8 + (tid >> 5);
    int l = tid & 31;
    int bm = g >> 10, n = g & 1023;
    const int* ip = idxb + (size_t)g * 10;
    const unsigned short* ekb = Ek + ((size_t)bm << 10) * 128 + l * 4;

    int e0 = ip[0], e1 = ip[1], e2 = ip[2], e3 = ip[3], e4 = ip[4];
    int e5 = ip[5], e6 = ip[6], e7 = ip[7], e8 = ip[8], e9 = ip[9];
    ushort4 u0 = *(const ushort4*)(ekb + (size_t)e0 * 128);
    ushort4 u1 = *(const ushort4*)(ekb + (size_t)e1 * 128);
    ushort4 u2 = *(const ushort4*)(ekb + (size_t)e2 * 128);
    ushort4 u3 = *(const ushort4*)(ekb + (size_t)e3 * 128);
    ushort4 u4 = *(const ushort4*)(ekb + (size_t)e4 * 128);
    ushort4 u5 = *(const ushort4*)(ekb + (size_t)e5 * 128);
    ushort4 u6 = *(const ushort4*)(ekb + (size_t)e6 * 128);
    ushort4 u7 = *(const ushort4*)(ekb + (size_t)e7 * 128);
    ushort4 u8 = *(const ushort4*)(ekb + (size_t)e8 * 128);
    ushort4 u9 = *(const ushort4*)(ekb + (size_t)e9 * 128);

    float4 acc;
    acc.x = bfu(u0.x) + bfu(u1.x) + bfu(u2.x) + bfu(u3.x) + bfu(u4.x)
          + bfu(u5.x) + bfu(u6.x) + bfu(u7.x) + bfu(u8.x) + bfu(u9.x);
    acc.y = bfu(u0.y) + bfu(u1.y) + bfu(u2.y) + bfu(u3.y) + bfu(u4.y)
          + bfu(u5.y) + bfu(u6.y) + bfu(u7.y) + bfu(u8.y) + bfu(u9.y);
    acc.z = bfu(u0.z) + bfu(u1.z) + bfu(u2.z) + bfu(u3.z) + bfu(u4.z)
          + bfu(u5.z) + bfu(u6.z) + bfu(u7.z) + bfu(u8.z) + bfu(u9.z);
    acc.w = bfu(u0.w) + bfu(u1.w) + bfu(u2.w) + bfu(u3.w) + bfu(u4.w)
          + bfu(u5.w) + bfu(u6.w) + bfu(u7.w) + bfu(u8.w) + bfu(u9.w);

    const float* hp  = Hc + (size_t)g * 10;
    const float* dcp = Dcv + (size_t)bm * 10;
    const float* ecp = Ec + (size_t)bm * 10 * 128 + l * 4;
#pragma unroll
    for (int c = 0; c < 10; ++c) {
        float d  = dcp[c];
        float hv = (d > 0.f) ? hp[c] / d : 0.f;
        float4 ec = *(const float4*)(ecp + c * 128);
        acc.x += hv * ec.x; acc.y += hv * ec.y;
        acc.z += hv * ec.z; acc.w += hv * ec.w;
    }
    float4 r;
    r.x = acc.x * (1.0f / 11.0f);
    r.y = acc.y * (1.0f / 11.0f);
    r.z = acc.z * (1.0f / 11.0f);
    r.w = acc.w * (1.0f / 11.0f);
    r.x = (r.x > 0.f) ? r.x : expm1f(r.x);
    r.y = (r.y > 0.f) ? r.y : expm1f(r.y);
    r.z = (r.z > 0.f) ? r.z : expm1f(r.z);
    r.w = (r.w > 0.f) ? r.w : expm1f(r.w);
    int b = bm >> 3, m = bm & 7;
    *(float4*)(out + (((size_t)b * NNODE + n) * 8 + m) * 128 + l * 4) = r;
}

// ---------------------------------------------------------------------------
extern "C" void kernel_launch(void* const* d_in, const int* in_sizes, int n_in,
                              void* d_out, int out_size, void* d_ws, size_t ws_size,
                              hipStream_t stream) {
    const void* x   = d_in[0];
    const void* Wp  = d_in[1];
    const void* Wpb = d_in[2];
    const void* Cm  = d_in[3];
    const void* Th  = d_in[4];
    const void* Thb = d_in[5];
    float* ws = (float*)d_ws;

    if (ws_size < OFF_END * sizeof(float)) return;

    _Float16* Zh = (_Float16*)(ws + OFF_Z);
    _Float16* Zl = (_Float16*)(ws + OFF_Z + 1048576);
    float* sqv  = ws + OFF_SQ;
    float* Hc   = ws + OFF_HC;
    int*   idxb = (int*)(ws + OFF_IDX);
    int*   cnt  = (int*)(ws + OFF_CNT);
    float* Ec   = ws + OFF_EC;
    float* Dcv  = ws + OFF_DCV;
    int*   offs = (int*)(ws + OFF_OFFS);
    int*   adj  = (int*)(ws + OFF_ADJ);
    int*   flag = (int*)(ws + OFF_FLAG);
    _Float16* WpH = (_Float16*)(ws + OFF_WPH);
    _Float16* WpL = (_Float16*)(ws + OFF_WPL);
    _Float16* ThH = (_Float16*)(ws + OFF_THH);
    _Float16* ThL = (_Float16*)(ws + OFF_THL);
    unsigned short* Ek = (unsigned short*)(ws + OFF_Z);  // overlays dead Zh/Zl
    float* Xt  = (float*)d_out;
    float* out = (float*)d_out;

    k_split    <<<96,   256, 0, stream>>>((const unsigned int*)x, Wp, Th, flag,
                                          WpH, WpL, ThH, ThL, cnt, Ec);
    k_proj     <<<1024, 256, 0, stream>>>(x, WpH, WpL, Wpb, Cm, flag, Zh, Zl, sqv, Hc);
    k_topktheta<<<2048, 256, 0, stream>>>(Zh, Zl, sqv, idxb, cnt,
                                          x, ThH, ThL, Thb, flag, Xt);
    k_csr      <<<32,   256, 0, stream>>>(cnt, idxb, offs, adj);
    k_edgeclus <<<4352, 256, 0, stream>>>(Xt, offs, cnt, adj, Ek, Hc, Ec, Dcv);
    k_final    <<<4096, 256, 0, stream>>>(Ek, Ec, Hc, Dcv, idxb, out);
}

// Round 15
// 236.801 us; speedup vs baseline: 1.1934x; 1.1934x over previous
//
#include <hip/hip_runtime.h>
#include <hip/hip_bf16.h>
#include <cstdint>
#include <cstddef>

// Problem constants
#define BMC 32    // B*M
#define NNODE 1024
#define DIN 128
#define PPROJ 64
#define NCLUS 10
#define FOUT 128
#define KNB 10

typedef _Float16 half8 __attribute__((ext_vector_type(8)));
typedef float f32x4 __attribute__((ext_vector_type(4)));

// Inputs: fp32 (probe-confirmed). Output: fp32. Internals fp32 except:
//  - Z stored as fp16 split pair Zh/Zl (lo scaled x2048) for MFMA Gram
//  - Ek bf16 (overlays dead Zh/Zl region after k_topk)
// X_trans fp32 (16 MB) lives in d_out; k_final overwrites d_out with output.
static const size_t OFF_Z    = 0;          // words [0,1048576): Zh fp16; [1048576,2097152): Zl fp16
static const size_t OFF_SQ   = 2097152;    // 32,768     ||Z||^2 fp32
static const size_t OFF_HC   = 2129920;    // 327,680    softmax cluster H fp32
static const size_t OFF_IDX  = 2457600;    // 327,680    (int) knn indices
static const size_t OFF_CNT  = 2785280;    // 32,768     (int) edge in-degree  [zeroed in k_split]
static const size_t OFF_FILL = 2818048;    // 32,768     hosts pre-split weights
static const size_t OFF_EC   = 2850816;    // 40,960     cluster edge feats    [zeroed in k_split]
static const size_t OFF_DCV  = 2891776;    // 320        cluster edge degrees  [zeroed in k_split]
static const size_t OFF_OFFS = 2892096;    // 32,768     (int) CSR offsets
static const size_t OFF_ADJ  = 2924864;    // 327,680    (int) CSR adjacency
static const size_t OFF_FLAG = 3252544;    // 1          (int) input-dtype flag
static const size_t OFF_END  = 3252608;
static const size_t OFF_WPH  = OFF_FILL;          // 4096 words  (8192 fp16)
static const size_t OFF_WPL  = OFF_FILL +  4096;  // 4096 words
static const size_t OFF_THH  = OFF_FILL +  8192;  // 8192 words  (16384 fp16)
static const size_t OFF_THL  = OFF_FILL + 16384;  // ends at +24576 < 32768

__device__ __forceinline__ float bfu(unsigned int lo16) {
    return __uint_as_float(lo16 << 16);
}
__device__ __forceinline__ float ldf(const void* p, size_t i, bool isbf) {
    return isbf ? bfu((unsigned int)((const unsigned short*)p)[i])
                : ((const float*)p)[i];
}
__device__ __forceinline__ unsigned short f2bf(float v) {
    __hip_bfloat16 h = __float2bfloat16(v);
    return *(unsigned short*)&h;
}

// --- top-k helpers: u64 sortable keys (R5-measured-best transform) --------
__device__ __forceinline__ unsigned long long mkkey(float v, int col) {
    unsigned int bits = __float_as_uint(v);
    unsigned int s = bits ^ (0x80000000u | (unsigned int)((int)bits >> 31));
    return ((unsigned long long)s << 32) | (unsigned int)col;
}
__device__ __forceinline__ void kcas(unsigned long long &a, unsigned long long &b) {
    bool c = b < a;
    unsigned long long t = c ? b : a;
    b = c ? a : b;
    a = t;
}
__device__ __forceinline__ void kmin(unsigned long long &a, unsigned long long b) {
    a = (b < a) ? b : a;
}

// ---------------------------------------------------------------------------
// R19: weight split + per-block probe + cnt/Ec/Dcv zeroing (unchanged).
// ---------------------------------------------------------------------------
__global__ __launch_bounds__(256) void k_split(const unsigned int* __restrict__ xw,
                                               const void* __restrict__ Wp,
                                               const void* __restrict__ Th,
                                               int* __restrict__ flag,
                                               _Float16* __restrict__ WpH,
                                               _Float16* __restrict__ WpL,
                                               _Float16* __restrict__ ThH,
                                               _Float16* __restrict__ ThL,
                                               int* __restrict__ cntz,
                                               float* __restrict__ EcZ) {
    __shared__ int red[256];
    int t = threadIdx.x;
    int c = 0;
    for (int i = t; i < 1024; i += 256) {
        float b = bfu(xw[i] & 0xffffu);
        float ab = fabsf(b);
        if (ab > 9.5e-7f && ab < 1.0e6f) c++;
    }
    red[t] = c;
    __syncthreads();
    for (int off = 128; off > 0; off >>= 1) {
        if (t < off) red[t] += red[t + off];
        __syncthreads();
    }
    const bool isbf = (red[0] >= 700);
    if (blockIdx.x == 0 && t == 0) flag[0] = isbf ? 1 : 0;

    int i = blockIdx.x * 256 + t;   // 0..24575
    cntz[i] = 0;
    if (i < 8192) cntz[i + 24576] = 0;        // cnt: 32768 words
    EcZ[i] = 0.0f;
    if (i < 16704) EcZ[i + 24576] = 0.0f;     // Ec+Dcv: 41280 words

    if (i < 8192) {
        float v = ldf(Wp, i, isbf);
        _Float16 h = (_Float16)v;
        WpH[i] = h;
        WpL[i] = (_Float16)((v - (float)h) * 2048.0f);
    } else {
        int j = i - 8192;
        float v = ldf(Th, j, isbf);
        _Float16 h = (_Float16)v;
        ThH[j] = h;
        ThL[j] = (_Float16)((v - (float)h) * 2048.0f);
    }
}

// ---------------------------------------------------------------------------
// Kernel 1 (R13, unchanged): Z = x_flat @ Wp^T + b via fp16-split MFMA.
// ---------------------------------------------------------------------------
__global__ __launch_bounds__(256) void k_proj(const void* __restrict__ x,
                                              const _Float16* __restrict__ WpH,
                                              const _Float16* __restrict__ WpL,
                                              const void* __restrict__ Wpb,
                                              const void* __restrict__ Cm,
                                              const int* __restrict__ flag,
                                              _Float16* __restrict__ Zh,
                                              _Float16* __restrict__ Zl,
                                              float* __restrict__ sqv,
                                              float* __restrict__ Hc) {
    __shared__ __align__(16) _Float16 wps[2][64][72];
    __shared__ __align__(16) _Float16 xsh[2][32][72];
    __shared__ float zs[32][68];
    __shared__ float cs[10][64];

    const bool isbf = (flag[0] != 0);
    int tid = threadIdx.x;
    int bi  = blockIdx.x;
    int bm  = bi >> 5;
    int n0  = (bi & 31) << 5;
    int b   = bm >> 3, m = bm & 7;

    int lane = tid & 63, wave = tid >> 6;
    int m16 = lane & 15, quad = lane >> 4;
    int rh = wave >> 1, ch = wave & 1;

    for (int e = tid; e < 640; e += 256) cs[e >> 6][e & 63] = ldf(Cm, e, isbf);

    f32x4 aH[2], aX[2];
#pragma unroll
    for (int t = 0; t < 2; ++t) {
        aH[t] = (f32x4){0.f, 0.f, 0.f, 0.f};
        aX[t] = (f32x4){0.f, 0.f, 0.f, 0.f};
    }

    for (int kc = 0; kc < 2; ++kc) {
        __syncthreads();
        for (int e = tid; e < 512; e += 256) {
            int p = e >> 3, c = e & 7;
            *(uint4*)&wps[0][p][c * 8] =
                *(const uint4*)(WpH + (size_t)p * 128 + kc * 64 + c * 8);
            *(uint4*)&wps[1][p][c * 8] =
                *(const uint4*)(WpL + (size_t)p * 128 + kc * 64 + c * 8);
        }
        for (int e = tid; e < 2048; e += 256) {
            int r = e >> 6, dk = e & 63;
            float v = ldf(x, (((size_t)b * NNODE + n0 + r) * 8 + m) * DIN + kc * 64 + dk, isbf);
            _Float16 h = (_Float16)v;
            xsh[0][r][dk] = h;
            xsh[1][r][dk] = (_Float16)((v - (float)h) * 2048.0f);
        }
        __syncthreads();
#pragma unroll
        for (int c32 = 0; c32 < 2; ++c32) {
            half8 Ah = *(const half8*)&xsh[0][rh * 16 + m16][c32 * 32 + quad * 8];
            half8 Al = *(const half8*)&xsh[1][rh * 16 + m16][c32 * 32 + quad * 8];
#pragma unroll
            for (int t = 0; t < 2; ++t) {
                int p = ch * 32 + t * 16 + m16;
                half8 Bh = *(const half8*)&wps[0][p][c32 * 32 + quad * 8];
                half8 Bl = *(const half8*)&wps[1][p][c32 * 32 + quad * 8];
                aH[t] = __builtin_amdgcn_mfma_f32_16x16x32_f16(Ah, Bh, aH[t], 0, 0, 0);
                aX[t] = __builtin_amdgcn_mfma_f32_16x16x32_f16(Al, Bh, aX[t], 0, 0, 0);
                aX[t] = __builtin_amdgcn_mfma_f32_16x16x32_f16(Ah, Bl, aX[t], 0, 0, 0);
            }
        }
    }

#pragma unroll
    for (int t = 0; t < 2; ++t) {
        int p = ch * 32 + t * 16 + m16;
        float bias = ldf(Wpb, p, isbf);
#pragma unroll
        for (int r = 0; r < 4; ++r) {
            int row = rh * 16 + quad * 4 + r;
            float v = aH[t][r] + aX[t][r] * (1.0f / 2048.0f) + bias;
            zs[row][p] = v;
            size_t off = ((size_t)bm * NNODE + n0 + row) * 64 + p;
            _Float16 h = (_Float16)v;
            Zh[off] = h;
            Zl[off] = (_Float16)((v - (float)h) * 2048.0f);
        }
    }
    __syncthreads();

    int row = tid >> 3, slot = tid & 7;
    int d0 = slot * 8;
    float sp = 0.f;
#pragma unroll
    for (int dd = 0; dd < 8; ++dd) { float z = zs[row][d0+dd]; sp += z * z; }
#pragma unroll
    for (int mm = 1; mm < 8; mm <<= 1) sp += __shfl_xor(sp, mm, 8);
    size_t g = (size_t)bm * NNODE + n0 + row;
    if (slot == 0) sqv[g] = sp;

    float sc[10];
#pragma unroll
    for (int c = 0; c < 10; ++c) {
        float pa = 0.f;
#pragma unroll
        for (int dd = 0; dd < 8; ++dd) pa += zs[row][d0+dd] * cs[c][d0+dd];
#pragma unroll
        for (int mm = 1; mm < 8; mm <<= 1) pa += __shfl_xor(pa, mm, 8);
        sc[c] = pa;
    }
    float mx = sc[0];
#pragma unroll
    for (int c = 1; c < 10; ++c) mx = fmaxf(mx, sc[c]);
    float ssum = 0.f;
#pragma unroll
    for (int c = 0; c < 10; ++c) { sc[c] = expf(sc[c] - mx); ssum += sc[c]; }
    float inv = 1.0f / ssum;
#pragma unroll
    for (int c = 0; c < 10; ++c)
        if ((c & 7) == slot) Hc[g * 10 + c] = sc[c] * inv;
}

// ---------------------------------------------------------------------------
// Kernel 3 (R21 = exact R11/R9-measured-best): fused Gram + top-K, 32 rows
// x 1024 cols per block (grid 1024), de-staged, counted-vmcnt ping-pong.
// ---------------------------------------------------------------------------
#define TOPK_SELECT(J0)                                                        \
  {                                                                            \
    unsigned long long b0 = mkkey(ST[(sslot     ) * 36 + srow], (J0) + sslot);        \
    unsigned long long b1 = mkkey(ST[(sslot +  8) * 36 + srow], (J0) + sslot + 8);    \
    unsigned long long b2 = mkkey(ST[(sslot + 16) * 36 + srow], (J0) + sslot + 16);   \
    unsigned long long b3 = mkkey(ST[(sslot + 24) * 36 + srow], (J0) + sslot + 24);   \
    unsigned long long b4 = mkkey(ST[(sslot + 32) * 36 + srow], (J0) + sslot + 32);   \
    unsigned long long b5 = mkkey(ST[(sslot + 40) * 36 + srow], (J0) + sslot + 40);   \
    unsigned long long b6 = mkkey(ST[(sslot + 48) * 36 + srow], (J0) + sslot + 48);   \
    unsigned long long b7 = mkkey(ST[(sslot + 56) * 36 + srow], (J0) + sslot + 56);   \
    kcas(b0, b1); kcas(b2, b3); kcas(b4, b5); kcas(b6, b7);                    \
    kcas(b0, b2); kcas(b1, b3); kcas(b4, b6); kcas(b5, b7);                    \
    kcas(b1, b2); kcas(b5, b6);                                                \
    kcas(b0, b4); kcas(b1, b5); kcas(b2, b6); kcas(b3, b7);                    \
    kcas(b2, b4); kcas(b3, b5);                                                \
    kcas(b1, b2); kcas(b3, b4); kcas(b5, b6);                                  \
    kmin(keys[2], b7); kmin(keys[3], b6); kmin(keys[4], b5); kmin(keys[5], b4);\
    kmin(keys[6], b3); kmin(keys[7], b2); kmin(keys[8], b1); kmin(keys[9], b0);\
    kcas(keys[0], keys[8]); kcas(keys[1], keys[9]);                            \
    kcas(keys[2], keys[6]); kcas(keys[3], keys[7]);                            \
    kcas(keys[4], keys[8]); kcas(keys[5], keys[9]);                            \
    kcas(keys[2], keys[4]); kcas(keys[3], keys[5]);                            \
    kcas(keys[6], keys[8]); kcas(keys[7], keys[9]);                            \
    kcas(keys[0], keys[1]); kcas(keys[2], keys[3]);                            \
    kcas(keys[4], keys[5]); kcas(keys[6], keys[7]); kcas(keys[8], keys[9]);    \
  }

#define TOPK_TILE(J0, CH0,CH1,CL0,CL1,CSQ, NH0,NH1,NL0,NL1,NSQ)                \
  {                                                                            \
    f32x4 acc  = {0.f, 0.f, 0.f, 0.f};                                         \
    f32x4 accx = {0.f, 0.f, 0.f, 0.f};                                         \
    acc  = __builtin_amdgcn_mfma_f32_16x16x32_f16(ah0, CH0, acc, 0, 0, 0);     \
    acc  = __builtin_amdgcn_mfma_f32_16x16x32_f16(ah1, CH1, acc, 0, 0, 0);     \
    accx = __builtin_amdgcn_mfma_f32_16x16x32_f16(al0, CH0, accx, 0, 0, 0);    \
    accx = __builtin_amdgcn_mfma_f32_16x16x32_f16(ah0, CL0, accx, 0, 0, 0);    \
    accx = __builtin_amdgcn_mfma_f32_16x16x32_f16(al1, CH1, accx, 0, 0, 0);    \
    accx = __builtin_amdgcn_mfma_f32_16x16x32_f16(ah1, CL1, accx, 0, 0, 0);    \
    f32x4 sc;                                                                  \
    _Pragma("unroll")                                                          \
    for (int r = 0; r < 4; ++r) {                                              \
      float g = acc[r] + accx[r] * (1.0f / 2048.0f);                           \
      sc[r] = fmaf(-2.0f, g, CSQ);                                             \
    }                                                                          \
    *(f32x4*)&ST[cl * 36 + quad * 4] = sc;                                     \
    f32x4 accB  = {0.f, 0.f, 0.f, 0.f};                                        \
    f32x4 accxB = {0.f, 0.f, 0.f, 0.f};                                        \
    accB  = __builtin_amdgcn_mfma_f32_16x16x32_f16(ah0b, CH0, accB, 0, 0, 0);  \
    accB  = __builtin_amdgcn_mfma_f32_16x16x32_f16(ah1b, CH1, accB, 0, 0, 0);  \
    accxB = __builtin_amdgcn_mfma_f32_16x16x32_f16(al0b, CH0, accxB, 0, 0, 0); \
    accxB = __builtin_amdgcn_mfma_f32_16x16x32_f16(ah0b, CL0, accxB, 0, 0, 0); \
    accxB = __builtin_amdgcn_mfma_f32_16x16x32_f16(al1b, CH1, accxB, 0, 0, 0); \
    accxB = __builtin_amdgcn_mfma_f32_16x16x32_f16(ah1b, CL1, accxB, 0, 0, 0); \
    _Pragma("unroll")                                                          \
    for (int r = 0; r < 4; ++r) {                                              \
      float g = accB[r] + accxB[r] * (1.0f / 2048.0f);                         \
      sc[r] = fmaf(-2.0f, g, CSQ);                                             \
    }                                                                          \
    *(f32x4*)&ST[cl * 36 + 16 + quad * 4] = sc;                                \
    {                                                                          \
      const _Float16* pnb = Zhb + (size_t)((J0) + 64 + cl) * 64 + quad * 8;    \
      const _Float16* pnl = Zlb + (size_t)((J0) + 64 + cl) * 64 + quad * 8;    \
      NH0 = *(const half8*)pnb;                                                \
      NH1 = *(const half8*)(pnb + 32);                                         \
      NL0 = *(const half8*)pnl;                                                \
      NL1 = *(const half8*)(pnl + 32);                                         \
      NSQ = sqb[(J0) + 64 + cl];                                               \
    }                                                                          \
    asm volatile("s_waitcnt lgkmcnt(0)" ::: "memory");                         \
    __builtin_amdgcn_s_barrier();                                              \
    asm volatile("" ::: "memory");                                             \
    TOPK_SELECT(J0);                                                           \
    asm volatile("" ::: "memory");                                             \
    __builtin_amdgcn_s_barrier();                                              \
    asm volatile("" ::: "memory");                                             \
  }

__global__ __launch_bounds__(256) void k_topk(const _Float16* __restrict__ Zh,
                                              const _Float16* __restrict__ Zl,
                                              const float* __restrict__ sqv,
                                              int* __restrict__ idxo,
                                              int* __restrict__ cnt) {
    __shared__ float ST[64 * 36];

    int tid = threadIdx.x;
    int bi  = blockIdx.x;
    int bm  = bi >> 5;
    int n0  = (bi & 31) << 5;
    const _Float16* Zhb = Zh + (size_t)bm * NNODE * 64;
    const _Float16* Zlb = Zl + (size_t)bm * NNODE * 64;
    const float*    sqb = sqv + (size_t)bm * NNODE;

    int lane = tid & 63, wave = tid >> 6;
    int m16 = lane & 15, quad = lane >> 4;
    int cl = wave * 16 + m16;

    half8 ah0, ah1, al0, al1, ah0b, ah1b, al0b, al1b;
    {
        size_t ab = (size_t)(n0 + m16) * 64 + quad * 8;
        ah0 = *(const half8*)(Zhb + ab);
        ah1 = *(const half8*)(Zhb + ab + 32);
        al0 = *(const half8*)(Zlb + ab);
        al1 = *(const half8*)(Zlb + ab + 32);
        size_t ab2 = ab + 16 * 64;
        ah0b = *(const half8*)(Zhb + ab2);
        ah1b = *(const half8*)(Zhb + ab2 + 32);
        al0b = *(const half8*)(Zlb + ab2);
        al1b = *(const half8*)(Zlb + ab2 + 32);
    }

    unsigned long long keys[10];
#pragma unroll
    for (int j = 0; j < 10; ++j) keys[j] = ~0ULL;

    int srow  = tid >> 3;    // 0..31: this thread's row
    int sslot = tid & 7;     // 8 threads per row

    // preload tile 0 B-set
    half8 cbh0, cbh1, cbl0, cbl1, nbh0, nbh1, nbl0, nbl1;
    float csq, nsq;
    {
        const _Float16* pb = Zhb + (size_t)cl * 64 + quad * 8;
        const _Float16* pl = Zlb + (size_t)cl * 64 + quad * 8;
        cbh0 = *(const half8*)pb;
        cbh1 = *(const half8*)(pb + 32);
        cbl0 = *(const half8*)pl;
        cbl1 = *(const half8*)(pl + 32);
        csq  = sqb[cl];
    }

    for (int tp = 0; tp < 8; ++tp) {
        int j0a = tp << 7;
        TOPK_TILE(j0a,      cbh0, cbh1, cbl0, cbl1, csq, nbh0, nbh1, nbl0, nbl1, nsq)
        TOPK_TILE(j0a + 64, nbh0, nbh1, nbl0, nbl1, nsq, cbh0, cbh1, cbl0, cbl1, csq)
    }

    size_t gr = (size_t)bm * NNODE + n0 + srow;
    for (int it = 0; it < 10; ++it) {
        unsigned long long mine = keys[0];
        unsigned long long best = mine;
#pragma unroll
        for (int mm = 1; mm < 8; mm <<= 1) {
            unsigned long long o = __shfl_xor(best, mm, 8);
            if (o < best) best = o;
        }
        if (best == mine) {
#pragma unroll
            for (int j = 0; j < 9; ++j) keys[j] = keys[j+1];
            keys[9] = ~0ULL;
            int col = (int)(best & 0xFFFFFFFFu);
            idxo[gr * KNB + it] = col;
            atomicAdd(&cnt[bm * NNODE + col], 1);
        }
    }
}
#undef TOPK_TILE
#undef TOPK_SELECT

// ---------------------------------------------------------------------------
// R20: HYBRID k_theta + k_csr. Blocks 0..31 build the CSR; blocks 32..1055
// run the Theta MFMA GEMM.
// ---------------------------------------------------------------------------
__global__ __launch_bounds__(256) void k_thetacsr(const void* __restrict__ x,
                                                  const _Float16* __restrict__ ThH,
                                                  const _Float16* __restrict__ ThL,
                                                  const void* __restrict__ Thb,
                                                  const int* __restrict__ flag,
                                                  float* __restrict__ Xt,
                                                  const int* __restrict__ cnt,
                                                  const int* __restrict__ idxb,
                                                  int* __restrict__ offs,
                                                  int* __restrict__ adj) {
    __shared__ __align__(16) _Float16 ths[2][128][72];
    __shared__ __align__(16) _Float16 xsh[32][72];
    __shared__ int part[256];
    __shared__ int fillL[1024];

    int tid = threadIdx.x;
    if (blockIdx.x < 32) {
        // ---- CSR path ----
        int bm = blockIdx.x, t = tid;
        int base = bm * 1024 + t * 4;
        int c0 = cnt[base], c1 = cnt[base+1], c2 = cnt[base+2], c3 = cnt[base+3];
        int ps = c0 + c1 + c2 + c3;
        part[t] = ps;
        __syncthreads();
        for (int off = 1; off < 256; off <<= 1) {
            int add = (t >= off) ? part[t - off] : 0;
            __syncthreads();
            part[t] += add;
            __syncthreads();
        }
        int e0 = part[t] - ps;
        int gb = bm * (NNODE * KNB);
        int o0 = gb + e0, o1 = o0 + c0, o2 = o1 + c1, o3 = o2 + c2;
        offs[base]   = o0;
        offs[base+1] = o1;
        offs[base+2] = o2;
        offs[base+3] = o3;
        fillL[t*4]   = o0;
        fillL[t*4+1] = o1;
        fillL[t*4+2] = o2;
        fillL[t*4+3] = o3;
        __syncthreads();
        int ibase = bm * (NNODE * KNB);
        for (int e = t; e < NNODE * KNB; e += 256) {
            int eidx = idxb[ibase + e];
            int pos = atomicAdd(&fillL[eidx], 1);
            adj[pos] = (bm << 10) + (e / 10);
        }
        return;
    }

    // ---- Theta path ----
    const bool isbf = (flag[0] != 0);
    int bi  = blockIdx.x - 32;
    int bm  = bi >> 5;
    int n0  = (bi & 31) << 5;
    int b   = bm >> 3, m = bm & 7;

    int lane = tid & 63, wave = tid >> 6;
    int m16 = lane & 15, quad = lane >> 4;
    int rh = wave >> 1, ch = wave & 1;

    f32x4 aH[4], aX[4];
#pragma unroll
    for (int t = 0; t < 4; ++t) {
        aH[t] = (f32x4){0.f, 0.f, 0.f, 0.f};
        aX[t] = (f32x4){0.f, 0.f, 0.f, 0.f};
    }

    for (int kc = 0; kc < 2; ++kc) {
        __syncthreads();
        for (int e = tid; e < 1024; e += 256) {
            int f = e >> 3, c = e & 7;
            *(uint4*)&ths[0][f][c * 8] =
                *(const uint4*)(ThH + (size_t)f * 128 + kc * 64 + c * 8);
            *(uint4*)&ths[1][f][c * 8] =
                *(const uint4*)(ThL + (size_t)f * 128 + kc * 64 + c * 8);
        }
        for (int e = tid; e < 2048; e += 256) {
            int r = e >> 6, dk = e & 63;
            float v = ldf(x, (((size_t)b * NNODE + n0 + r) * 8 + m) * DIN + kc * 64 + dk, isbf);
            xsh[r][dk] = (_Float16)v;
        }
        __syncthreads();
#pragma unroll
        for (int c32 = 0; c32 < 2; ++c32) {
            half8 Ah = *(const half8*)&xsh[rh * 16 + m16][c32 * 32 + quad * 8];
#pragma unroll
            for (int t = 0; t < 4; ++t) {
                int f = ch * 64 + t * 16 + m16;
                half8 Bh = *(const half8*)&ths[0][f][c32 * 32 + quad * 8];
                half8 Bl = *(const half8*)&ths[1][f][c32 * 32 + quad * 8];
                aH[t] = __builtin_amdgcn_mfma_f32_16x16x32_f16(Ah, Bh, aH[t], 0, 0, 0);
                aX[t] = __builtin_amdgcn_mfma_f32_16x16x32_f16(Ah, Bl, aX[t], 0, 0, 0);
            }
        }
    }
#pragma unroll
    for (int t = 0; t < 4; ++t) {
        int f = ch * 64 + t * 16 + m16;
        float bias = ldf(Thb, f, isbf);
        size_t rb = (size_t)bm * NNODE + n0 + rh * 16 + quad * 4;
#pragma unroll
        for (int r = 0; r < 4; ++r) {
            Xt[(rb + r) * 128 + f] = aH[t][r] + aX[t][r] * (1.0f / 2048.0f) + bias;
        }
    }
}

// ---------------------------------------------------------------------------
// R19: MERGED edge-gather + cluster-edge kernel (unchanged).
// ---------------------------------------------------------------------------
__global__ __launch_bounds__(256) void k_edgeclus(const float* __restrict__ Xt,
                                                  const int* __restrict__ offs,
                                                  const int* __restrict__ cnt,
                                                  const int* __restrict__ adj,
                                                  unsigned short* __restrict__ Ek,
                                                  const float* __restrict__ Hc,
                                                  float* __restrict__ Ec,
                                                  float* __restrict__ Dcv) {
    __shared__ float hcs[128][12];
    int tid = threadIdx.x;
    int bi  = blockIdx.x;

    if (bi < 256) {
        int bm = bi >> 3;
        int ch = bi & 7;
        int n0 = ch * 128;

        for (int e = tid; e < 1280; e += 256) {
            int r = e / 10, c = e - r * 10;
            hcs[r][c] = Hc[((size_t)bm * NNODE + n0 + r) * 10 + c];
        }
        __syncthreads();

        int f = tid & 127;
        int h = tid >> 7;
        int c0 = h * 5;
        float acc[5]  = {0.f,0.f,0.f,0.f,0.f};
        float dacc[5] = {0.f,0.f,0.f,0.f,0.f};
#pragma unroll 2
        for (int n = 0; n < 128; ++n) {
            float xv = Xt[((size_t)bm * NNODE + n0 + n) * 128 + f];
#pragma unroll
            for (int j = 0; j < 5; ++j) {
                float hv = hcs[n][c0 + j];
                acc[j]  = fmaf(hv, xv, acc[j]);
                dacc[j] += hv;
            }
        }
#pragma unroll
        for (int j = 0; j < 5; ++j)
            atomicAdd(&Ec[((size_t)bm * 10 + c0 + j) * 128 + f], acc[j]);
        if (f == 0) {
#pragma unroll
            for (int j = 0; j < 5; ++j) atomicAdd(&Dcv[bm * 10 + c0 + j], dacc[j]);
        }
        return;
    }

    int ebi = bi - 256;
    int swz = (ebi & 7) * 512 + (ebi >> 3);
    int e = swz * 8 + (tid >> 5);
    int l = tid & 31;
    int start = offs[e];
    int num = cnt[e];
    float4 acc = {0.f, 0.f, 0.f, 0.f};
    if (num > 0) {
        int nm1 = num - 1;
        int gidx[16];
#pragma unroll
        for (int j = 0; j < 16; ++j) {
            int jj = (j < nm1) ? j : nm1;
            gidx[j] = adj[start + jj];
        }
#pragma unroll
        for (int j = 0; j < 16; ++j) {
            float4 a = *(const float4*)(Xt + (size_t)gidx[j] * 128 + l * 4);
            float w = (j < num) ? 1.0f : 0.0f;
            acc.x = fmaf(w, a.x, acc.x);
            acc.y = fmaf(w, a.y, acc.y);
            acc.z = fmaf(w, a.z, acc.z);
            acc.w = fmaf(w, a.w, acc.w);
        }
        int i = 16;
        for (; i + 1 < num; i += 2) {
            int g0 = adj[start + i];
            int g1 = adj[start + i + 1];
            float4 a = *(const float4*)(Xt + (size_t)g0 * 128 + l * 4);
            float4 b = *(const float4*)(Xt + (size_t)g1 * 128 + l * 4);
            acc.x += a.x + b.x; acc.y += a.y + b.y;
            acc.z += a.z + b.z; acc.w += a.w + b.w;
        }
        if (i < num) {
            int g0 = adj[start + i];
            float4 a = *(const float4*)(Xt + (size_t)g0 * 128 + l * 4);
            acc.x += a.x; acc.y += a.y; acc.z += a.z; acc.w += a.w;
        }
    }
    float scale = (num > 0) ? 1.0f / (float)num : 0.0f;
    ushort4 o;
    o.x = f2bf(acc.x * scale);
    o.y = f2bf(acc.y * scale);
    o.z = f2bf(acc.z * scale);
    o.w = f2bf(acc.w * scale);
    *(ushort4*)(Ek + (size_t)e * 128 + l * 4) = o;
}

// ---------------------------------------------------------------------------
// Final (R16, unchanged): 32 threads/node, XCD swizzle, folded 1/Dcv,
// batched 10-wide kNN gather.
// ---------------------------------------------------------------------------
__global__ __launch_bounds__(256) void k_final(const unsigned short* __restrict__ Ek,
                                               const float* __restrict__ Ec,
                                               const float* __restrict__ Hc,
                                               const float* __restrict__ Dcv,
                                               const int* __restrict__ idxb,
                                               float* __restrict__ out) {
    int tid = threadIdx.x;
    int bi  = blockIdx.x;
    int swz = (bi & 7) * 512 + (bi >> 3);
    int g = swz * 8 + (tid >> 5);
    int l = tid & 31;
    int bm = g >> 10, n = g & 1023;
    const int* ip = idxb + (size_t)g * 10;
    const unsigned short* ekb = Ek + ((size_t)bm << 10) * 128 + l * 4;

    int e0 = ip[0], e1 = ip[1], e2 = ip[2], e3 = ip[3], e4 = ip[4];
    int e5 = ip[5], e6 = ip[6], e7 = ip[7], e8 = ip[8], e9 = ip[9];
    ushort4 u0 = *(const ushort4*)(ekb + (size_t)e0 * 128);
    ushort4 u1 = *(const ushort4*)(ekb + (size_t)e1 * 128);
    ushort4 u2 = *(const ushort4*)(ekb + (size_t)e2 * 128);
    ushort4 u3 = *(const ushort4*)(ekb + (size_t)e3 * 128);
    ushort4 u4 = *(const ushort4*)(ekb + (size_t)e4 * 128);
    ushort4 u5 = *(const ushort4*)(ekb + (size_t)e5 * 128);
    ushort4 u6 = *(const ushort4*)(ekb + (size_t)e6 * 128);
    ushort4 u7 = *(const ushort4*)(ekb + (size_t)e7 * 128);
    ushort4 u8 = *(const ushort4*)(ekb + (size_t)e8 * 128);
    ushort4 u9 = *(const ushort4*)(ekb + (size_t)e9 * 128);

    float4 acc;
    acc.x = bfu(u0.x) + bfu(u1.x) + bfu(u2.x) + bfu(u3.x) + bfu(u4.x)
          + bfu(u5.x) + bfu(u6.x) + bfu(u7.x) + bfu(u8.x) + bfu(u9.x);
    acc.y = bfu(u0.y) + bfu(u1.y) + bfu(u2.y) + bfu(u3.y) + bfu(u4.y)
          + bfu(u5.y) + bfu(u6.y) + bfu(u7.y) + bfu(u8.y) + bfu(u9.y);
    acc.z = bfu(u0.z) + bfu(u1.z) + bfu(u2.z) + bfu(u3.z) + bfu(u4.z)
          + bfu(u5.z) + bfu(u6.z) + bfu(u7.z) + bfu(u8.z) + bfu(u9.z);
    acc.w = bfu(u0.w) + bfu(u1.w) + bfu(u2.w) + bfu(u3.w) + bfu(u4.w)
          + bfu(u5.w) + bfu(u6.w) + bfu(u7.w) + bfu(u8.w) + bfu(u9.w);

    const float* hp  = Hc + (size_t)g * 10;
    const float* dcp = Dcv + (size_t)bm * 10;
    const float* ecp = Ec + (size_t)bm * 10 * 128 + l * 4;
#pragma unroll
    for (int c = 0; c < 10; ++c) {
        float d  = dcp[c];
        float hv = (d > 0.f) ? hp[c] / d : 0.f;
        float4 ec = *(const float4*)(ecp + c * 128);
        acc.x += hv * ec.x; acc.y += hv * ec.y;
        acc.z += hv * ec.z; acc.w += hv * ec.w;
    }
    float4 r;
    r.x = acc.x * (1.0f / 11.0f);
    r.y = acc.y * (1.0f / 11.0f);
    r.z = acc.z * (1.0f / 11.0f);
    r.w = acc.w * (1.0f / 11.0f);
    r.x = (r.x > 0.f) ? r.x : expm1f(r.x);
    r.y = (r.y > 0.f) ? r.y : expm1f(r.y);
    r.z = (r.z > 0.f) ? r.z : expm1f(r.z);
    r.w = (r.w > 0.f) ? r.w : expm1f(r.w);
    int b = bm >> 3, m = bm & 7;
    *(float4*)(out + (((size_t)b * NNODE + n) * 8 + m) * 128 + l * 4) = r;
}

// ---------------------------------------------------------------------------
extern "C" void kernel_launch(void* const* d_in, const int* in_sizes, int n_in,
                              void* d_out, int out_size, void* d_ws, size_t ws_size,
                              hipStream_t stream) {
    const void* x   = d_in[0];
    const void* Wp  = d_in[1];
    const void* Wpb = d_in[2];
    const void* Cm  = d_in[3];
    const void* Th  = d_in[4];
    const void* Thb = d_in[5];
    float* ws = (float*)d_ws;

    if (ws_size < OFF_END * sizeof(float)) return;

    _Float16* Zh = (_Float16*)(ws + OFF_Z);
    _Float16* Zl = (_Float16*)(ws + OFF_Z + 1048576);
    float* sqv  = ws + OFF_SQ;
    float* Hc   = ws + OFF_HC;
    int*   idxb = (int*)(ws + OFF_IDX);
    int*   cnt  = (int*)(ws + OFF_CNT);
    float* Ec   = ws + OFF_EC;
    float* Dcv  = ws + OFF_DCV;
    int*   offs = (int*)(ws + OFF_OFFS);
    int*   adj  = (int*)(ws + OFF_ADJ);
    int*   flag = (int*)(ws + OFF_FLAG);
    _Float16* WpH = (_Float16*)(ws + OFF_WPH);
    _Float16* WpL = (_Float16*)(ws + OFF_WPL);
    _Float16* ThH = (_Float16*)(ws + OFF_THH);
    _Float16* ThL = (_Float16*)(ws + OFF_THL);
    unsigned short* Ek = (unsigned short*)(ws + OFF_Z);  // overlays dead Zh/Zl
    float* Xt  = (float*)d_out;
    float* out = (float*)d_out;

    k_split   <<<96,   256, 0, stream>>>((const unsigned int*)x, Wp, Th, flag,
                                         WpH, WpL, ThH, ThL, cnt, Ec);
    k_proj    <<<1024, 256, 0, stream>>>(x, WpH, WpL, Wpb, Cm, flag, Zh, Zl, sqv, Hc);
    k_topk    <<<1024, 256, 0, stream>>>(Zh, Zl, sqv, idxb, cnt);
    k_thetacsr<<<1056, 256, 0, stream>>>(x, ThH, ThL, Thb, flag, Xt, cnt, idxb, offs, adj);
    k_edgeclus<<<4352, 256, 0, stream>>>(Xt, offs, cnt, adj, Ek, Hc, Ec, Dcv);
    k_final   <<<4096, 256, 0, stream>>>(Ek, Ec, Hc, Dcv, idxb, out);
}